// Round 1
// baseline (820.793 us; speedup 1.0000x reference)
//
#include <hip/hip_runtime.h>

#define HDIM 20
#define NSTEP 5

__device__ __forceinline__ float fast_sigmoid(float x) {
    return 1.0f / (1.0f + __expf(-x));
}
__device__ __forceinline__ float fast_tanh(float x) {
    // tanh(x) = 1 - 2/(exp(2x)+1); saturates correctly at +/-inf
    return 1.0f - 2.0f / (__expf(2.0f * x) + 1.0f);
}

__global__ __launch_bounds__(256) void navi_kernel(
    const float* __restrict__ inp,     // [B]
    const float* __restrict__ hidden,  // [2,B,H]
    const float* __restrict__ cell,    // [2,B,H]
    const float* __restrict__ W_ih1,   // [80,2]
    const float* __restrict__ W_hh1,   // [80,20]
    const float* __restrict__ b_ih1,   // [80]
    const float* __restrict__ b_hh1,   // [80]
    const float* __restrict__ W_ih2,   // [80,20]
    const float* __restrict__ W_hh2,   // [80,20]
    const float* __restrict__ b_ih2,   // [80]
    const float* __restrict__ b_hh2,   // [80]
    const float* __restrict__ W_out,   // [20]
    const float* __restrict__ b_out,   // [1]
    float* __restrict__ out,           // [5B | h0 | h1 | c0 | c1]
    int B)
{
    __shared__ __align__(16) float sWih1[160];
    __shared__ __align__(16) float sWhh1[1600];
    __shared__ __align__(16) float sWih2[1600];
    __shared__ __align__(16) float sWhh2[1600];
    __shared__ __align__(16) float sWout[HDIM];
    __shared__ __align__(16) float sB1[80];
    __shared__ __align__(16) float sB2[80];

    // ---- cooperative weight staging ----
    for (int i = threadIdx.x; i < 160;  i += 256) sWih1[i] = W_ih1[i];
    for (int i = threadIdx.x; i < 1600; i += 256) sWhh1[i] = W_hh1[i];
    for (int i = threadIdx.x; i < 1600; i += 256) sWih2[i] = W_ih2[i];
    for (int i = threadIdx.x; i < 1600; i += 256) sWhh2[i] = W_hh2[i];
    if (threadIdx.x < 80)  sB1[threadIdx.x] = b_ih1[threadIdx.x] + b_hh1[threadIdx.x];
    if (threadIdx.x >= 128 && threadIdx.x < 208) {
        int r = threadIdx.x - 128;
        sB2[r] = b_ih2[r] + b_hh2[r];
    }
    if (threadIdx.x >= 224 && threadIdx.x < 224 + HDIM) {
        int r = threadIdx.x - 224;
        sWout[r] = W_out[r];
    }
    __syncthreads();

    int b = blockIdx.x * 256 + threadIdx.x;
    if (b >= B) return;

    // ---- preproc ----
    float x = inp[b];
    float ax = fabsf(x);
    const float thr = 4.5399929762484854e-05f;    // expf(-10)
    bool keep = ax >= thr;
    float x0 = keep ? (__logf(ax + 1e-8f) * 0.1f) : -1.0f;
    float x1 = keep ? (x > 0.0f ? 1.0f : -1.0f) : (22026.465794806718f * x);

    // ---- load h0_prev, c0_prev (float4 x5, 16B aligned since b*80 % 16 == 0) ----
    const float4* h0p4 = (const float4*)(hidden + (size_t)b * HDIM);
    const float4* c0p4 = (const float4*)(cell   + (size_t)b * HDIM);
    float hp[HDIM], cp[HDIM];
    #pragma unroll
    for (int k4 = 0; k4 < 5; k4++) {
        float4 hv = h0p4[k4];
        float4 cv = c0p4[k4];
        hp[k4*4+0] = hv.x; hp[k4*4+1] = hv.y; hp[k4*4+2] = hv.z; hp[k4*4+3] = hv.w;
        cp[k4*4+0] = cv.x; cp[k4*4+1] = cv.y; cp[k4*4+2] = cv.z; cp[k4*4+3] = cv.w;
    }

    // ---- LSTM cell 1 ----
    const float4* Whh1v = (const float4*)sWhh1;  // row r -> [r*5 .. r*5+5)
    float hA[HDIM];
    #pragma unroll
    for (int j = 0; j < HDIM; j++) {
        float gi = sB1[j]      + x0 * sWih1[2*j]        + x1 * sWih1[2*j+1];
        float gf = sB1[j + 20] + x0 * sWih1[2*(j+20)]   + x1 * sWih1[2*(j+20)+1];
        float gg = sB1[j + 40] + x0 * sWih1[2*(j+40)]   + x1 * sWih1[2*(j+40)+1];
        float go = sB1[j + 60] + x0 * sWih1[2*(j+60)]   + x1 * sWih1[2*(j+60)+1];
        #pragma unroll
        for (int k4 = 0; k4 < 5; k4++) {
            float4 wi = Whh1v[(j     )*5 + k4];
            float4 wf = Whh1v[(j + 20)*5 + k4];
            float4 wg = Whh1v[(j + 40)*5 + k4];
            float4 wo = Whh1v[(j + 60)*5 + k4];
            float h0v = hp[k4*4+0], h1v = hp[k4*4+1], h2v = hp[k4*4+2], h3v = hp[k4*4+3];
            gi += wi.x*h0v + wi.y*h1v + wi.z*h2v + wi.w*h3v;
            gf += wf.x*h0v + wf.y*h1v + wf.z*h2v + wf.w*h3v;
            gg += wg.x*h0v + wg.y*h1v + wg.z*h2v + wg.w*h3v;
            go += wo.x*h0v + wo.y*h1v + wo.z*h2v + wo.w*h3v;
        }
        float cn = fast_sigmoid(gf) * cp[j] + fast_sigmoid(gi) * fast_tanh(gg);
        cp[j] = cn;                                   // c0_new
        hA[j] = fast_sigmoid(go) * fast_tanh(cn);     // h0_new
    }

    // ---- store h0_new, c0_new ----
    size_t oh0 = (size_t)NSTEP * B + (size_t)b * HDIM;
    size_t oh1 = oh0 + (size_t)B * HDIM;
    size_t oc0 = oh1 + (size_t)B * HDIM;   // offset of c0 region for this b
    size_t oc1 = oc0 + (size_t)B * HDIM;
    {
        float4* oH = (float4*)(out + oh0);
        float4* oC = (float4*)(out + oc0);
        #pragma unroll
        for (int k4 = 0; k4 < 5; k4++) {
            oH[k4] = make_float4(hA[k4*4+0], hA[k4*4+1], hA[k4*4+2], hA[k4*4+3]);
            oC[k4] = make_float4(cp[k4*4+0], cp[k4*4+1], cp[k4*4+2], cp[k4*4+3]);
        }
    }

    // ---- load h1_prev, c1_prev ----
    const float4* h1p4 = (const float4*)(hidden + (size_t)B * HDIM + (size_t)b * HDIM);
    const float4* c1p4 = (const float4*)(cell   + (size_t)B * HDIM + (size_t)b * HDIM);
    #pragma unroll
    for (int k4 = 0; k4 < 5; k4++) {
        float4 hv = h1p4[k4];
        float4 cv = c1p4[k4];
        hp[k4*4+0] = hv.x; hp[k4*4+1] = hv.y; hp[k4*4+2] = hv.z; hp[k4*4+3] = hv.w;
        cp[k4*4+0] = cv.x; cp[k4*4+1] = cv.y; cp[k4*4+2] = cv.z; cp[k4*4+3] = cv.w;
    }

    // ---- LSTM cell 2 (input = hA) ----
    const float4* Wih2v = (const float4*)sWih2;
    const float4* Whh2v = (const float4*)sWhh2;
    float hB[HDIM];
    #pragma unroll
    for (int j = 0; j < HDIM; j++) {
        float gi = sB2[j];
        float gf = sB2[j + 20];
        float gg = sB2[j + 40];
        float go = sB2[j + 60];
        #pragma unroll
        for (int k4 = 0; k4 < 5; k4++) {
            float a0 = hA[k4*4+0], a1 = hA[k4*4+1], a2 = hA[k4*4+2], a3 = hA[k4*4+3];
            float h0v = hp[k4*4+0], h1v = hp[k4*4+1], h2v = hp[k4*4+2], h3v = hp[k4*4+3];
            float4 ui = Wih2v[(j     )*5 + k4];
            float4 uf = Wih2v[(j + 20)*5 + k4];
            float4 ug = Wih2v[(j + 40)*5 + k4];
            float4 uo = Wih2v[(j + 60)*5 + k4];
            gi += ui.x*a0 + ui.y*a1 + ui.z*a2 + ui.w*a3;
            gf += uf.x*a0 + uf.y*a1 + uf.z*a2 + uf.w*a3;
            gg += ug.x*a0 + ug.y*a1 + ug.z*a2 + ug.w*a3;
            go += uo.x*a0 + uo.y*a1 + uo.z*a2 + uo.w*a3;
            float4 wi = Whh2v[(j     )*5 + k4];
            float4 wf = Whh2v[(j + 20)*5 + k4];
            float4 wg = Whh2v[(j + 40)*5 + k4];
            float4 wo = Whh2v[(j + 60)*5 + k4];
            gi += wi.x*h0v + wi.y*h1v + wi.z*h2v + wi.w*h3v;
            gf += wf.x*h0v + wf.y*h1v + wf.z*h2v + wf.w*h3v;
            gg += wg.x*h0v + wg.y*h1v + wg.z*h2v + wg.w*h3v;
            go += wo.x*h0v + wo.y*h1v + wo.z*h2v + wo.w*h3v;
        }
        float cn = fast_sigmoid(gf) * cp[j] + fast_sigmoid(gi) * fast_tanh(gg);
        cp[j] = cn;                                   // c1_new
        hB[j] = fast_sigmoid(go) * fast_tanh(cn);     // h1_new
    }

    // ---- store h1_new, c1_new ----
    {
        float4* oH = (float4*)(out + oh1);
        float4* oC = (float4*)(out + oc1);
        #pragma unroll
        for (int k4 = 0; k4 < 5; k4++) {
            oH[k4] = make_float4(hB[k4*4+0], hB[k4*4+1], hB[k4*4+2], hB[k4*4+3]);
            oC[k4] = make_float4(cp[k4*4+0], cp[k4*4+1], cp[k4*4+2], cp[k4*4+3]);
        }
    }

    // ---- output head: (h1 . W_out + b_out) * [1..5] ----
    float acc = b_out[0];
    #pragma unroll
    for (int j = 0; j < HDIM; j++) acc += hB[j] * sWout[j];
    float* o = out + (size_t)b * NSTEP;
    #pragma unroll
    for (int s = 0; s < NSTEP; s++) o[s] = acc * (float)(s + 1);
}

extern "C" void kernel_launch(void* const* d_in, const int* in_sizes, int n_in,
                              void* d_out, int out_size, void* d_ws, size_t ws_size,
                              hipStream_t stream) {
    const float* inp    = (const float*)d_in[0];
    const float* hidden = (const float*)d_in[1];
    const float* cell   = (const float*)d_in[2];
    const float* W_ih1  = (const float*)d_in[3];
    const float* W_hh1  = (const float*)d_in[4];
    const float* b_ih1  = (const float*)d_in[5];
    const float* b_hh1  = (const float*)d_in[6];
    const float* W_ih2  = (const float*)d_in[7];
    const float* W_hh2  = (const float*)d_in[8];
    const float* b_ih2  = (const float*)d_in[9];
    const float* b_hh2  = (const float*)d_in[10];
    const float* W_out  = (const float*)d_in[11];
    const float* b_out  = (const float*)d_in[12];
    float* out = (float*)d_out;

    int B = in_sizes[0];
    int grid = (B + 255) / 256;
    navi_kernel<<<grid, 256, 0, stream>>>(
        inp, hidden, cell,
        W_ih1, W_hh1, b_ih1, b_hh1,
        W_ih2, W_hh2, b_ih2, b_hh2,
        W_out, b_out, out, B);
}